// Round 1
// baseline (1241.226 us; speedup 1.0000x reference)
//
#include <hip/hip_runtime.h>
#include <hip/hip_fp16.h>
#include <cstddef>
#include <cstdint>

typedef _Float16 f16;
typedef _Float16 f16x8 __attribute__((ext_vector_type(8)));
typedef _Float16 f16x4 __attribute__((ext_vector_type(4)));
typedef float    f32x4 __attribute__((ext_vector_type(4)));

#define BM 128
#define BN 128
#define BK 32
#define LDT 40   // padded LDS row stride in fp16 elems (80 B = 20 banks; 16B-aligned frags)

// ---------------------------------------------------------------------------
// TN GEMM: C[M][N] = A[M][K] @ B[N][K]^T  (+bias[n]) (+relu)
// A row-major (lda in TA elems), B row-major N rows x K (ldb), C row-major (ldc).
// TA/TB in {float, f16} (f32 converted to fp16 during LDS staging). TC in {float, f16}.
// 256 threads = 4 waves (2x2), each wave owns 64x64 out = 4x4 mfma_16x16x32 frags.
// ---------------------------------------------------------------------------
template<typename TA, typename TB, bool BIAS, bool RELU, typename TC>
__global__ __launch_bounds__(256, 2)
void gemm_tn(const TA* __restrict__ A, int lda,
             const TB* __restrict__ B, int ldb,
             TC* __restrict__ C, int ldc,
             const float* __restrict__ bias, int K)
{
  __shared__ f16 As[BM][LDT];
  __shared__ f16 Bs[BN][LDT];
  const int tid  = threadIdx.x;
  const int lane = tid & 63;
  const int wid  = tid >> 6;
  const int wr   = wid >> 1;      // wave row (0..1)
  const int wc   = wid & 1;       // wave col (0..1)
  const int m0   = blockIdx.x * BM;
  const int n0   = blockIdx.y * BN;

  const int sr = tid >> 1;        // staging tile row 0..127
  const int sh = (tid & 1) << 4;  // staging k-offset 0 or 16

  f32x4 acc[4][4] = {};

  for (int k0 = 0; k0 < K; k0 += BK) {
    // ---- stage A tile [128 x 32] ----
    {
      f16x8 w0, w1;
      if constexpr (sizeof(TA) == 4) {
        const float4* s = (const float4*)(A + (size_t)(m0 + sr) * lda + k0 + sh);
        float4 a = s[0], b = s[1], c = s[2], d = s[3];
        w0[0]=(f16)a.x; w0[1]=(f16)a.y; w0[2]=(f16)a.z; w0[3]=(f16)a.w;
        w0[4]=(f16)b.x; w0[5]=(f16)b.y; w0[6]=(f16)b.z; w0[7]=(f16)b.w;
        w1[0]=(f16)c.x; w1[1]=(f16)c.y; w1[2]=(f16)c.z; w1[3]=(f16)c.w;
        w1[4]=(f16)d.x; w1[5]=(f16)d.y; w1[6]=(f16)d.z; w1[7]=(f16)d.w;
      } else {
        const f16x8* s = (const f16x8*)(A + (size_t)(m0 + sr) * lda + k0 + sh);
        w0 = s[0]; w1 = s[1];
      }
      *(f16x8*)&As[sr][sh]     = w0;
      *(f16x8*)&As[sr][sh + 8] = w1;
    }
    // ---- stage B tile [128 x 32] ----
    {
      f16x8 w0, w1;
      if constexpr (sizeof(TB) == 4) {
        const float4* s = (const float4*)(B + (size_t)(n0 + sr) * ldb + k0 + sh);
        float4 a = s[0], b = s[1], c = s[2], d = s[3];
        w0[0]=(f16)a.x; w0[1]=(f16)a.y; w0[2]=(f16)a.z; w0[3]=(f16)a.w;
        w0[4]=(f16)b.x; w0[5]=(f16)b.y; w0[6]=(f16)b.z; w0[7]=(f16)b.w;
        w1[0]=(f16)c.x; w1[1]=(f16)c.y; w1[2]=(f16)c.z; w1[3]=(f16)c.w;
        w1[4]=(f16)d.x; w1[5]=(f16)d.y; w1[6]=(f16)d.z; w1[7]=(f16)d.w;
      } else {
        const f16x8* s = (const f16x8*)(B + (size_t)(n0 + sr) * ldb + k0 + sh);
        w0 = s[0]; w1 = s[1];
      }
      *(f16x8*)&Bs[sr][sh]     = w0;
      *(f16x8*)&Bs[sr][sh + 8] = w1;
    }
    __syncthreads();

    // ---- fragments + MFMA ----
    // A frag (16x32): row = lane&15, k = (lane>>4)*8 + j  -> contiguous b128 read
    // B frag (32x16): col = lane&15, k = (lane>>4)*8 + j  -> Bs holds B^T, same read
    const int fr = lane & 15;
    const int kg = (lane >> 4) << 3;
    f16x8 af[4], bf[4];
#pragma unroll
    for (int i = 0; i < 4; i++)
      af[i] = *(const f16x8*)&As[wr * 64 + i * 16 + fr][kg];
#pragma unroll
    for (int j = 0; j < 4; j++)
      bf[j] = *(const f16x8*)&Bs[wc * 64 + j * 16 + fr][kg];
#pragma unroll
    for (int i = 0; i < 4; i++)
#pragma unroll
      for (int j = 0; j < 4; j++)
        acc[i][j] = __builtin_amdgcn_mfma_f32_16x16x32_f16(af[i], bf[j], acc[i][j], 0, 0, 0);
    __syncthreads();
  }

  // ---- epilogue: D layout col = lane&15, row = (lane>>4)*4 + r (m89-verified) ----
  const int fr = lane & 15;
  const int rg = (lane >> 4) << 2;
#pragma unroll
  for (int i = 0; i < 4; i++) {
#pragma unroll
    for (int j = 0; j < 4; j++) {
      const int col = n0 + wc * 64 + j * 16 + fr;
      float bv = 0.f;
      if constexpr (BIAS) bv = bias[col];
#pragma unroll
      for (int r = 0; r < 4; r++) {
        const int row = m0 + wr * 64 + i * 16 + rg + r;
        float v = acc[i][j][r] + bv;
        if constexpr (RELU) v = fmaxf(v, 0.f);
        C[(size_t)row * ldc + col] = (TC)v;
      }
    }
  }
}

// ---------------------------------------------------------------------------
// Transpose f32 -> fp16: in[R][Cn] f32; outT[Cn][R] fp16; optional outD[R][Cn] fp16.
// ---------------------------------------------------------------------------
template<bool WRITE_D>
__global__ __launch_bounds__(256)
void transpose_f32_f16(const float* __restrict__ in, int R, int Cn,
                       f16* __restrict__ outT, f16* __restrict__ outD)
{
  __shared__ float t[32][33];
  const int r0 = blockIdx.x * 32;
  const int c0 = blockIdx.y * 32;
  const int c  = threadIdx.x & 31;
  const int rq = threadIdx.x >> 5;   // 0..7
#pragma unroll
  for (int i = 0; i < 4; i++) {
    const int r = rq + i * 8;
    const float v = in[(size_t)(r0 + r) * Cn + c0 + c];
    t[r][c] = v;
    if constexpr (WRITE_D) outD[(size_t)(r0 + r) * Cn + c0 + c] = (f16)v;
  }
  __syncthreads();
#pragma unroll
  for (int i = 0; i < 4; i++) {
    const int r = rq + i * 8;
    outT[(size_t)(c0 + r) * R + r0 + c] = (f16)t[c][r];
  }
}

// ---------------------------------------------------------------------------
// Row softmax over 2048 f32 scores; writes normalized P as fp16 IN-PLACE over
// the f32 row (reads complete before first barrier; writes after last).
// ---------------------------------------------------------------------------
__global__ __launch_bounds__(256)
void softmax_rows(float* __restrict__ S)
{
  float* row = S + (size_t)blockIdx.x * 2048;
  const int t = threadIdx.x;
  const float4 v0 = ((const float4*)row)[t];
  const float4 v1 = ((const float4*)row)[t + 256];

  float m = fmaxf(fmaxf(fmaxf(v0.x, v0.y), fmaxf(v0.z, v0.w)),
                  fmaxf(fmaxf(v1.x, v1.y), fmaxf(v1.z, v1.w)));
#pragma unroll
  for (int off = 32; off > 0; off >>= 1) m = fmaxf(m, __shfl_xor(m, off));
  __shared__ float red[8];
  if ((t & 63) == 0) red[t >> 6] = m;
  __syncthreads();
  m = fmaxf(fmaxf(red[0], red[1]), fmaxf(red[2], red[3]));

  float e0 = __expf(v0.x - m), e1 = __expf(v0.y - m), e2 = __expf(v0.z - m), e3 = __expf(v0.w - m);
  float e4 = __expf(v1.x - m), e5 = __expf(v1.y - m), e6 = __expf(v1.z - m), e7 = __expf(v1.w - m);
  float s = ((e0 + e1) + (e2 + e3)) + ((e4 + e5) + (e6 + e7));
#pragma unroll
  for (int off = 32; off > 0; off >>= 1) s += __shfl_xor(s, off);
  if ((t & 63) == 0) red[4 + (t >> 6)] = s;
  __syncthreads();
  const float inv = 1.f / (red[4] + red[5] + red[6] + red[7]);

  f16x4 o0, o1;
  o0[0] = (f16)(e0 * inv); o0[1] = (f16)(e1 * inv); o0[2] = (f16)(e2 * inv); o0[3] = (f16)(e3 * inv);
  o1[0] = (f16)(e4 * inv); o1[1] = (f16)(e5 * inv); o1[2] = (f16)(e6 * inv); o1[3] = (f16)(e7 * inv);
  f16x4* orow = (f16x4*)row;
  orow[t]       = o0;   // elems 4t..4t+3
  orow[t + 256] = o1;   // elems 1024+4t..
}

// ---------------------------------------------------------------------------
extern "C" void kernel_launch(void* const* d_in, const int* in_sizes, int n_in,
                              void* d_out, int out_size, void* d_ws, size_t ws_size,
                              hipStream_t stream)
{
  const float* x1   = (const float*)d_in[0];
  const float* x2   = (const float*)d_in[1];
  const float* U    = (const float*)d_in[2];
  const float* bias = (const float*)d_in[3];
  const float* fcw  = (const float*)d_in[4];
  const float* fcb  = (const float*)d_in[5];
  float* out = (float*)d_out;

  const int S = 2048, D = 1024, E = 512, B = 8;
  const size_t MB = 1ull << 20;

  // ws layout (per-batch reuse): UT 2MB | Y 4MB | X1h 4MB | X1T 4MB | O 4MB | Sb 16MB = 34MB
  char* w = (char*)d_ws;
  f16*   UT  = (f16*)(w);
  f16*   Y   = (f16*)(w + 2 * MB);
  f16*   X1h = (f16*)(w + 6 * MB);
  f16*   X1T = (f16*)(w + 10 * MB);
  f16*   O   = (f16*)(w + 14 * MB);
  float* Sb  = (float*)(w + 18 * MB);

  // s-chunk so the score buffer fits; probe ws tier via U-transpose grid.z
  int SC;
  if (ws_size >= 36 * MB)      SC = 2048;
  else if (ws_size >= 23 * MB) SC = 512;
  else                         SC = 128;
  const int tier = (ws_size >= 280 * MB) ? 3 : (ws_size >= 100 * MB) ? 2
                 : (ws_size >= 36 * MB)  ? 1 : 0;

  // U [d][e] -> UT [e][d] fp16 (grid.z = 1+tier: duplicate writes of same data,
  // deterministic; encodes ws tier in the dispatch record for profiling)
  transpose_f32_f16<false><<<dim3(32, 32, 1 + tier), 256, 0, stream>>>(U, D, D, UT, nullptr);

  for (int b = 0; b < B; b++) {
    const float* x1b = x1 + (size_t)b * S * D;
    const float* x2b = x2 + (size_t)b * S * D;

    // x1_b -> X1T [d][t] + X1h [t][d] fp16
    transpose_f32_f16<true><<<dim3(64, 32), 256, 0, stream>>>(x1b, S, D, X1T, X1h);

    // K1: Y = x2_b @ U + bias   (A=x2 f32, B=UT fp16 [e][d])
    gemm_tn<float, f16, true, false, f16><<<dim3(16, 8), 256, 0, stream>>>(
        x2b, D, UT, D, Y, D, bias, D);

    for (int s0 = 0; s0 < S; s0 += SC) {
      // K2: Sb = Y'[s0:] @ x1^T   (K = e = 1024)
      gemm_tn<f16, f16, false, false, float><<<dim3(SC / 128, S / 128), 256, 0, stream>>>(
          Y + (size_t)s0 * D, D, X1h, D, Sb, S, nullptr, D);
      // K3: softmax rows, P fp16 in-place
      softmax_rows<<<dim3(SC), 256, 0, stream>>>(Sb);
      // K4: O = P @ x1   (A=P fp16 lda=4096, B=X1T [d][t], K = t = 2048)
      gemm_tn<f16, f16, false, false, f16><<<dim3(SC / 128, D / 128), 256, 0, stream>>>(
          (const f16*)Sb, 2 * S, X1T, S, O, D, nullptr, S);
      // K5: out = relu(O @ fc_w^T + fc_b)   (B=fc_w f32 [e][d])
      gemm_tn<f16, float, true, true, float><<<dim3(SC / 128, E / 128), 256, 0, stream>>>(
          O, D, fcw, D, out + ((size_t)b * S + s0) * E, E, fcb, D);
    }
  }
}